// Round 2
// baseline (5376.942 us; speedup 1.0000x reference)
//
#include <hip/hip_runtime.h>
#include <hip/hip_bf16.h>

// HeteroNet on MI355X — round 2: workspace-hardened (245 MiB peak), exact-factored.
// Algebra: (1) segment_sum((base*x_src)@Wn) == segment_sum(base*x_src)@Wn
//   -> per-edge work is elementwise; GEMMs run on nodes, not edges.
// (2) edge_repr@W1 = xl_sum[src]@W1a + xp_sum[dst]@W1b + d*(W_el@W1c)
//   -> precompute node projections h_l/h_p (bf16); per-edge just gather+relu.
// Round-1 aborted with a GPU fault; prime suspect was d_ws overflow (513 MB used).
// This round: bf16 node states + time-aliased h buffers -> 245 MiB peak, and all
// memsets replaced with a zeroing kernel (graph-capture paranoia).

#define NLn 50000
#define NPn 150000
#define En  500000

__device__ __forceinline__ float bf2f(unsigned short u){ return __uint_as_float(((unsigned)u) << 16); }
__device__ __forceinline__ float bflo(unsigned u){ return __uint_as_float(u << 16); }
__device__ __forceinline__ float bfhi(unsigned u){ return __uint_as_float(u & 0xffff0000u); }
__device__ __forceinline__ unsigned short f2bf(float f){
  __hip_bfloat16 h = __float2bfloat16(f);
  return *reinterpret_cast<unsigned short*>(&h);
}
// order-preserving float->uint encoding; enc(v) > 0 for every finite v,
// so enc==0 marks "empty segment" (matches reference isfinite->0 mask).
__device__ __forceinline__ unsigned encf(float f){
  unsigned u = __float_as_uint(f);
  return (u & 0x80000000u) ? ~u : (u | 0x80000000u);
}

// grid-stride zero fill (u32 granularity; all our regions are 4B-multiple)
__global__ __launch_bounds__(256) void k_zero(unsigned* __restrict__ p, long n){
  long i = (long)blockIdx.x*256 + threadIdx.x;
  long stride = (long)gridDim.x*256;
  for (; i < n; i += stride) p[i] = 0u;
}

// out[n,c] = sum_k X[n,k] * W[k,c]   ([N,44]@[44,128]) -> bf16
__global__ __launch_bounds__(256) void k_embed(const float* __restrict__ X,
    const float* __restrict__ Wn, unsigned short* __restrict__ out){
  int gid = blockIdx.x*256 + threadIdx.x;
  int n = gid >> 7, c = gid & 127;
  const float* xr = X + (size_t)n*44;
  float acc = 0.f;
  #pragma unroll
  for (int k=0;k<44;k++) acc += xr[k]*Wn[k*128+c];
  out[(size_t)n*128 + c] = f2bf(acc);
}

__global__ __launch_bounds__(256) void k_deg(const int* __restrict__ src,
    const int* __restrict__ dst, float* __restrict__ degl, float* __restrict__ degp){
  int e = blockIdx.x*256 + threadIdx.x;
  if (e >= En) return;
  atomicAdd(&degl[src[e]], 1.f);
  atomicAdd(&degp[dst[e]], 1.f);
}

// v[j] = sum_r W_el[r] * W1[(256+r)*512 + j]
__global__ void k_vvec(const float* __restrict__ Wel, const float* __restrict__ W1,
                       float* __restrict__ v){
  int j = blockIdx.x*256 + threadIdx.x;
  if (j >= 512) return;
  float s = 0.f;
  #pragma unroll
  for (int r=0;r<8;r++) s += Wel[r]*W1[(256+r)*512 + j];
  v[j] = s;
}

// per edge e: base = silu(rbf(d_e) @ Wb + bb); acc[si[e]] += base * xsrc[gi[e]]
// 2 edges per 256-thread block (thread = channel c, sub = which edge).
__global__ __launch_bounds__(256) void k_scatter(const float* __restrict__ ea,
    const int* __restrict__ gi, const int* __restrict__ si,
    const unsigned short* __restrict__ xsrc, float* __restrict__ acc,
    const float* __restrict__ Wb, const float* __restrict__ bb){
  __shared__ float rbf[2][8];
  __shared__ int g2[2], s2[2];
  int c = threadIdx.x & 127, sub = threadIdx.x >> 7;
  int e = blockIdx.x*2 + sub;
  if (c < 8){
    float d = ea[e];
    float a = (d - 0.7142857143f*(float)c) * 1.6f;   // mu=linspace(0,5,8), sigma=5/8
    rbf[sub][c] = expf(-a*a);
  }
  if (c == 8) g2[sub] = gi[e];
  if (c == 9) s2[sub] = si[e];
  __syncthreads();
  float s = bb[c];
  #pragma unroll
  for (int j=0;j<8;j++) s += rbf[sub][j]*Wb[j*128 + c];
  float base = s / (1.f + expf(-s));                 // silu
  float val = base * bf2f(xsrc[(size_t)g2[sub]*128 + c]);
  atomicAdd(&acc[(size_t)s2[sub]*128 + c], val);
}

// x = lrelu(x @ Ws + (acc/max(deg,1)) @ Wn + b); xsum += x     (in place, bf16)
// 16 nodes per block, K=256 (concat x|agg), thread (c, hh) owns 8 nodes.
#define UPD_M 16
__global__ __launch_bounds__(256) void k_update(unsigned short* __restrict__ x,
    const float* __restrict__ accb, const float* __restrict__ deg,
    const float* __restrict__ Wss, const float* __restrict__ Wnn,
    const float* __restrict__ bias, unsigned short* __restrict__ xsum){
  __shared__ float xs[UPD_M][260];   // [m][k]; row stride 260 floats keeps 16B align
  int tid = threadIdx.x, c = tid & 127, hh = tid >> 7;
  int nb = blockIdx.x * UPD_M;
  for (int m=0;m<UPD_M;m++){
    int n = nb + m;
    if (hh == 0) xs[m][c] = bf2f(x[(size_t)n*128 + c]);
    else         xs[m][128 + c] = accb[(size_t)n*128 + c] / fmaxf(deg[n], 1.f);
  }
  __syncthreads();
  int m0 = hh*8;
  float accv[8] = {0,0,0,0,0,0,0,0};
  for (int k=0;k<128;k+=4){
    float w0 = Wss[(k+0)*128+c], w1 = Wss[(k+1)*128+c],
          w2 = Wss[(k+2)*128+c], w3 = Wss[(k+3)*128+c];
    #pragma unroll
    for (int m=0;m<8;m++){
      const float4 xv = *(const float4*)&xs[m0+m][k];
      accv[m] += xv.x*w0 + xv.y*w1 + xv.z*w2 + xv.w*w3;
    }
  }
  for (int k=0;k<128;k+=4){
    float w0 = Wnn[(k+0)*128+c], w1 = Wnn[(k+1)*128+c],
          w2 = Wnn[(k+2)*128+c], w3 = Wnn[(k+3)*128+c];
    #pragma unroll
    for (int m=0;m<8;m++){
      const float4 xv = *(const float4*)&xs[m0+m][128+k];
      accv[m] += xv.x*w0 + xv.y*w1 + xv.z*w2 + xv.w*w3;
    }
  }
  float bc = bias[c];
  #pragma unroll
  for (int m=0;m<8;m++){
    int n = nb + m0 + m;
    float v = accv[m] + bc;
    v = (v > 0.f) ? v : 0.01f*v;                     // leaky_relu 0.01
    size_t off = (size_t)n*128 + c;
    x[off] = f2bf(v);
    xsum[off] = f2bf(bf2f(xsum[off]) + v);           // owned by this thread; no race
  }
}

// h = xsum @ W1part  ([N,128]@[128,512]) -> bf16 rows; thread owns j=2*tid,2*tid+1
#define HP_M 16
__global__ __launch_bounds__(256) void k_hproj(const unsigned short* __restrict__ xsum,
    const float* __restrict__ W1p, unsigned* __restrict__ hout){
  __shared__ float xs[HP_M][132];
  int tid = threadIdx.x;
  int nb = blockIdx.x * HP_M;
  if (tid < 128){
    for (int m=0;m<HP_M;m++) xs[m][tid] = bf2f(xsum[(size_t)(nb+m)*128 + tid]);
  }
  __syncthreads();
  float a0[HP_M], a1[HP_M];
  #pragma unroll
  for (int m=0;m<HP_M;m++){ a0[m]=0.f; a1[m]=0.f; }
  int j2 = tid*2;
  for (int k=0;k<128;k+=4){
    float2 w0 = *(const float2*)&W1p[(k+0)*512 + j2];
    float2 w1 = *(const float2*)&W1p[(k+1)*512 + j2];
    float2 w2 = *(const float2*)&W1p[(k+2)*512 + j2];
    float2 w3 = *(const float2*)&W1p[(k+3)*512 + j2];
    #pragma unroll
    for (int m=0;m<HP_M;m++){
      const float4 xv = *(const float4*)&xs[m][k];
      a0[m] += xv.x*w0.x + xv.y*w1.x + xv.z*w2.x + xv.w*w3.x;
      a1[m] += xv.x*w0.y + xv.y*w1.y + xv.z*w2.y + xv.w*w3.y;
    }
  }
  #pragma unroll
  for (int m=0;m<HP_M;m++){
    unsigned pack = (unsigned)f2bf(a0[m]) | ((unsigned)f2bf(a1[m]) << 16);
    hout[(size_t)(nb+m)*256 + tid] = pack;
  }
}

// fused edge MLP + segment reductions. 16 edges/block.
// h = relu(h_l[src]+h_p[dst]+d*v+b1); m = h@W2+b2; w = tanh(m@Wm+bm);
// out[batch] += w*m (atomicAdd); mmax[batch] = max(m) (ordered-uint atomicMax)
#define RO_T 16
__global__ __launch_bounds__(256) void k_readout(
    const unsigned* __restrict__ hl, const unsigned* __restrict__ hp,
    const float* __restrict__ ea, const int* __restrict__ esrc,
    const int* __restrict__ edst, const int* __restrict__ lbatch,
    const float* __restrict__ vvec, const float* __restrict__ b1,
    const float* __restrict__ W2, const float* __restrict__ b2,
    const float* __restrict__ Wm, const float* __restrict__ bm,
    float* __restrict__ outw, unsigned* __restrict__ mmax){
  __shared__ float hs[RO_T][512];
  __shared__ float ms[RO_T][128];
  __shared__ int bsh[RO_T];
  int tid = threadIdx.x;
  int eb = blockIdx.x * RO_T;
  int j2 = tid*2;
  float2 vv = *(const float2*)&vvec[j2];
  float2 bv = *(const float2*)&b1[j2];
  for (int m=0;m<RO_T;m++){
    int e = eb + m;
    int s = esrc[e], dd = edst[e];
    float d = ea[e];
    if (tid == 0) bsh[m] = lbatch[s];
    unsigned ua = hl[(size_t)s*256 + tid];
    unsigned ub = hp[(size_t)dd*256 + tid];
    float2 hv;
    hv.x = fmaxf(bflo(ua) + bflo(ub) + d*vv.x + bv.x, 0.f);
    hv.y = fmaxf(bfhi(ua) + bfhi(ub) + d*vv.y + bv.y, 0.f);
    *(float2*)&hs[m][j2] = hv;
  }
  __syncthreads();
  int c = tid & 127, hh = tid >> 7, m0 = hh*8;
  float acc[8] = {0,0,0,0,0,0,0,0};
  for (int k=0;k<512;k+=4){
    float w0 = W2[(k+0)*128+c], w1 = W2[(k+1)*128+c],
          w2 = W2[(k+2)*128+c], w3 = W2[(k+3)*128+c];
    #pragma unroll
    for (int m=0;m<8;m++){
      const float4 hv4 = *(const float4*)&hs[m0+m][k];
      acc[m] += hv4.x*w0 + hv4.y*w1 + hv4.z*w2 + hv4.w*w3;
    }
  }
  float b2c = b2[c];
  #pragma unroll
  for (int m=0;m<8;m++) ms[m0+m][c] = acc[m] + b2c;
  __syncthreads();
  float ac2[8] = {0,0,0,0,0,0,0,0};
  for (int k=0;k<128;k+=4){
    float w0 = Wm[(k+0)*128+c], w1 = Wm[(k+1)*128+c],
          w2 = Wm[(k+2)*128+c], w3 = Wm[(k+3)*128+c];
    #pragma unroll
    for (int m=0;m<8;m++){
      const float4 mv = *(const float4*)&ms[m0+m][k];
      ac2[m] += mv.x*w0 + mv.y*w1 + mv.z*w2 + mv.w*w3;
    }
  }
  float bmc = bm[c];
  #pragma unroll
  for (int m=0;m<8;m++){
    float mval = ms[m0+m][c];
    float t = tanhf(ac2[m] + bmc);
    int b = bsh[m0+m];
    atomicAdd(&outw[b*256 + c], t*mval);
    atomicMax(&mmax[b*128 + c], encf(mval));
  }
}

__global__ __launch_bounds__(256) void k_final(const unsigned* __restrict__ mmax,
    float* __restrict__ out){
  int gid = blockIdx.x*256 + threadIdx.x;   // 32768 = 256 graphs * 128 ch
  unsigned enc = mmax[gid];
  float v;
  if (enc == 0u) v = 0.f;                                   // empty segment
  else if (enc & 0x80000000u) v = __uint_as_float(enc & 0x7FFFFFFFu);
  else v = __uint_as_float(~enc);
  int g = gid >> 7, cc = gid & 127;
  out[g*256 + 128 + cc] = v;
}

extern "C" void kernel_launch(void* const* d_in, const int* in_sizes, int n_in,
                              void* d_out, int out_size, void* d_ws, size_t ws_size,
                              hipStream_t stream) {
  const float* x_l    = (const float*)d_in[0];
  const float* x_p    = (const float*)d_in[1];
  const float* ea     = (const float*)d_in[2];
  const int*   esrc   = (const int*)d_in[3];
  const int*   edst   = (const int*)d_in[4];
  const int*   lbatch = (const int*)d_in[5];
  const float* W_node = (const float*)d_in[6];
  const float* W_el   = (const float*)d_in[7];
  const float* Wb     = (const float*)d_in[8];
  const float* bb     = (const float*)d_in[9];
  const float* Wn     = (const float*)d_in[10];
  const float* Ws     = (const float*)d_in[11];
  const float* bconv  = (const float*)d_in[12];
  const float* W1     = (const float*)d_in[13];
  const float* b1     = (const float*)d_in[14];
  const float* W2     = (const float*)d_in[15];
  const float* b2     = (const float*)d_in[16];
  const float* Wm     = (const float*)d_in[17];
  const float* bm     = (const float*)d_in[18];

  // ---- workspace layout (decimal byte offsets), peak 256,933,120 B = 245 MiB ----
  // Phase A (conv loop):             Phase B/C (readout), time-aliased:
  //   [0        ..  12.8e6) xl bf16    [0       ..  51.2e6) h_l bf16
  //   [12.8e6   ..  51.2e6) xp bf16    [51.2e6  .. 204.8e6) h_p bf16
  //   [51.2e6   ..  76.8e6) acc_l f32
  //   [76.8e6   .. 153.6e6) acc_p f32
  // persistent:
  //   [204.8e6 .. 217.6e6) xl_s bf16   [217.6e6 .. 256.0e6) xp_s bf16
  //   [256.0e6 .. +200e3) deg_l  [256.2e6 .. +600e3) deg_p
  //   [256.8e6 .. +2048) vvec    [256,802,048 .. +131072) mmax
  char* w = (char*)d_ws;
  unsigned short* xl   = (unsigned short*)(w + 0);
  unsigned short* xp   = (unsigned short*)(w + 12800000);
  float*    acc_l = (float*)(w + 51200000);
  float*    acc_p = (float*)(w + 76800000);
  unsigned* h_l   = (unsigned*)(w + 0);            // aliases xl+xp (dead after loop)
  unsigned* h_p   = (unsigned*)(w + 51200000);     // aliases acc_l+acc_p + fresh tail
  unsigned short* xl_s = (unsigned short*)(w + 204800000);
  unsigned short* xp_s = (unsigned short*)(w + 217600000);
  float*    deg_l = (float*)(w + 256000000);
  float*    deg_p = (float*)(w + 256200000);
  float*    vvec  = (float*)(w + 256800000);
  unsigned* mmax  = (unsigned*)(w + 256802048);

  float* out = (float*)d_out;

  // zero: xl_s+xp_s (contiguous 51.2e6 B), deg_l+deg_p (contiguous 800e3 B),
  //       mmax (131072 B), d_out (262144 B)
  k_zero<<<1024, 256, 0, stream>>>((unsigned*)(w + 204800000), 51200000/4);
  k_zero<<<256, 256, 0, stream>>>((unsigned*)(w + 256000000), 800000/4);
  k_zero<<<128, 256, 0, stream>>>(mmax, 131072/4);
  k_zero<<<256, 256, 0, stream>>>((unsigned*)d_out, 262144/4);

  k_embed<<<25000, 256, 0, stream>>>(x_l, W_node, xl);
  k_embed<<<75000, 256, 0, stream>>>(x_p, W_node, xp);
  k_deg<<<(En+255)/256, 256, 0, stream>>>(esrc, edst, deg_l, deg_p);
  k_vvec<<<2, 256, 0, stream>>>(W_el, W1, vvec);

  for (int l = 0; l < 3; ++l){
    int ilp = 2*l, ipl = 2*l + 1;
    // zero acc_l + acc_p (contiguous 102.4e6 B)
    k_zero<<<2048, 256, 0, stream>>>((unsigned*)(w + 51200000), 102400000/4);
    // ligand->protein: gather xl[esrc], scatter to acc_p[edst]
    k_scatter<<<En/2, 256, 0, stream>>>(ea, esrc, edst, xl, acc_p,
                                        Wb + ilp*1024, bb + ilp*128);
    // protein->ligand: gather xp[edst], scatter to acc_l[esrc]
    k_scatter<<<En/2, 256, 0, stream>>>(ea, edst, esrc, xp, acc_l,
                                        Wb + ipl*1024, bb + ipl*128);
    k_update<<<NPn/UPD_M, 256, 0, stream>>>(xp, acc_p, deg_p,
        Ws + ilp*16384, Wn + ilp*16384, bconv + ilp*128, xp_s);
    k_update<<<NLn/UPD_M, 256, 0, stream>>>(xl, acc_l, deg_l,
        Ws + ipl*16384, Wn + ipl*16384, bconv + ipl*128, xl_s);
  }

  // h_l overwrites xl/xp region; h_p overwrites acc region (+fresh tail) — both dead.
  k_hproj<<<NLn/HP_M, 256, 0, stream>>>(xl_s, W1, h_l);             // W1 rows 0..127
  k_hproj<<<NPn/HP_M, 256, 0, stream>>>(xp_s, W1 + 128*512, h_p);   // W1 rows 128..255

  k_readout<<<En/RO_T, 256, 0, stream>>>(h_l, h_p, ea, esrc, edst, lbatch,
                                         vvec, b1, W2, b2, Wm, bm, out, mmax);
  k_final<<<128, 256, 0, stream>>>(mmax, out);
}

// Round 3
// 4352.545 us; speedup vs baseline: 1.2354x; 1.2354x over previous
//
#include <hip/hip_runtime.h>
#include <hip/hip_bf16.h>

// HeteroNet on MI355X — round 3: MFMA readout + batch-sorted edges.
// R2 profile: k_readout 2.2ms, VALUBusy 87%, MfmaUtil 0, WRITE_SIZE 500MB.
// Fixes: (a) edge MLP GEMMs on bf16 MFMA (16x16x32), W2/Wm pre-transposed bf16;
//        (b) counting-sort edges by graph batch -> run-length-flushed segment
//            reductions (128M atomics -> ~8M) + ligand-gather locality.

#define NLn 50000
#define NPn 150000
#define En  500000

typedef __attribute__((ext_vector_type(8))) short short8;
typedef __attribute__((ext_vector_type(4))) float float4v;

__device__ __forceinline__ float bf2f(unsigned short u){ return __uint_as_float(((unsigned)u) << 16); }
__device__ __forceinline__ float bflo(unsigned u){ return __uint_as_float(u << 16); }
__device__ __forceinline__ float bfhi(unsigned u){ return __uint_as_float(u & 0xffff0000u); }
__device__ __forceinline__ unsigned short f2bf(float f){
  __hip_bfloat16 h = __float2bfloat16(f);
  return *reinterpret_cast<unsigned short*>(&h);
}
// order-preserving float->uint; enc(v)>0 for all finite v, so 0 == "empty segment"
__device__ __forceinline__ unsigned encf(float f){
  unsigned u = __float_as_uint(f);
  return (u & 0x80000000u) ? ~u : (u | 0x80000000u);
}

__global__ __launch_bounds__(256) void k_zero(unsigned* __restrict__ p, long n){
  long i = (long)blockIdx.x*256 + threadIdx.x;
  long stride = (long)gridDim.x*256;
  for (; i < n; i += stride) p[i] = 0u;
}

// out[n,c] = sum_k X[n,k]*W[k,c]  ([N,44]@[44,128]) -> bf16
__global__ __launch_bounds__(256) void k_embed(const float* __restrict__ X,
    const float* __restrict__ Wn, unsigned short* __restrict__ out){
  int gid = blockIdx.x*256 + threadIdx.x;
  int n = gid >> 7, c = gid & 127;
  const float* xr = X + (size_t)n*44;
  float acc = 0.f;
  #pragma unroll
  for (int k=0;k<44;k++) acc += xr[k]*Wn[k*128+c];
  out[(size_t)n*128 + c] = f2bf(acc);
}

__global__ __launch_bounds__(256) void k_deg(const int* __restrict__ src,
    const int* __restrict__ dst, float* __restrict__ degl, float* __restrict__ degp){
  int e = blockIdx.x*256 + threadIdx.x;
  if (e >= En) return;
  atomicAdd(&degl[src[e]], 1.f);
  atomicAdd(&degp[dst[e]], 1.f);
}

// v[j] = sum_r W_el[r] * W1[(256+r)*512 + j]
__global__ void k_vvec(const float* __restrict__ Wel, const float* __restrict__ W1,
                       float* __restrict__ v){
  int j = blockIdx.x*256 + threadIdx.x;
  if (j >= 512) return;
  float s = 0.f;
  #pragma unroll
  for (int r=0;r<8;r++) s += Wel[r]*W1[(256+r)*512 + j];
  v[j] = s;
}

// w2t[n][k] = bf16(W2[k][n])   (512x128 -> 128x512)
__global__ __launch_bounds__(256) void k_w2t(const float* __restrict__ W2,
    unsigned short* __restrict__ w2t){
  int gid = blockIdx.x*256 + threadIdx.x;   // 65536
  int n = gid >> 9, k = gid & 511;
  w2t[n*512 + k] = f2bf(W2[k*128 + n]);
}
// wmt[n][k] = bf16(Wm[k][n])   (128x128)
__global__ __launch_bounds__(256) void k_wmt(const float* __restrict__ Wm,
    unsigned short* __restrict__ wmt){
  int gid = blockIdx.x*256 + threadIdx.x;   // 16384
  int n = gid >> 7, k = gid & 127;
  wmt[n*128 + k] = f2bf(Wm[k*128 + n]);
}

// ---- counting sort of edges by batch = lbatch[esrc[e]] (256 bins) ----
__global__ __launch_bounds__(256) void k_hist(const int* __restrict__ esrc,
    const int* __restrict__ lbatch, unsigned* __restrict__ hist){
  __shared__ unsigned lh[256];
  int tid = threadIdx.x;
  lh[tid] = 0u; __syncthreads();
  int e = blockIdx.x*256 + tid;
  if (e < En) atomicAdd(&lh[lbatch[esrc[e]]], 1u);
  __syncthreads();
  if (lh[tid]) atomicAdd(&hist[tid], lh[tid]);
}
__global__ void k_scan(const unsigned* __restrict__ hist, unsigned* __restrict__ cursor){
  __shared__ unsigned tmp[256];
  int t = threadIdx.x;
  tmp[t] = hist[t]; __syncthreads();
  for (int off=1; off<256; off<<=1){
    unsigned v = (t >= off) ? tmp[t-off] : 0u;
    __syncthreads();
    tmp[t] += v;
    __syncthreads();
  }
  cursor[t] = tmp[t] - hist[t];   // exclusive prefix
}
__global__ __launch_bounds__(256) void k_sortscatter(const int* __restrict__ esrc,
    const int* __restrict__ edst, const float* __restrict__ ea,
    const int* __restrict__ lbatch, unsigned* __restrict__ cursor,
    int* __restrict__ es_s, int* __restrict__ ed_s, float* __restrict__ ea_s,
    int* __restrict__ eb_s){
  int e = blockIdx.x*256 + threadIdx.x;
  if (e >= En) return;
  int s = esrc[e], d = edst[e];
  int b = lbatch[s];
  unsigned pos = atomicAdd(&cursor[b], 1u);
  es_s[pos] = s; ed_s[pos] = d; ea_s[pos] = ea[e]; eb_s[pos] = b;
}

// per edge e: base = silu(rbf(d)@Wb+bb); acc[si[e]] += base * xsrc[gi[e]]
__global__ __launch_bounds__(256) void k_scatter(const float* __restrict__ ea,
    const int* __restrict__ gi, const int* __restrict__ si,
    const unsigned short* __restrict__ xsrc, float* __restrict__ acc,
    const float* __restrict__ Wb, const float* __restrict__ bb){
  __shared__ float rbf[2][8];
  __shared__ int g2[2], s2[2];
  int c = threadIdx.x & 127, sub = threadIdx.x >> 7;
  int e = blockIdx.x*2 + sub;
  if (c < 8){
    float d = ea[e];
    float a = (d - 0.7142857143f*(float)c) * 1.6f;   // mu=linspace(0,5,8), sigma=5/8
    rbf[sub][c] = expf(-a*a);
  }
  if (c == 8) g2[sub] = gi[e];
  if (c == 9) s2[sub] = si[e];
  __syncthreads();
  float s = bb[c];
  #pragma unroll
  for (int j=0;j<8;j++) s += rbf[sub][j]*Wb[j*128 + c];
  float base = s / (1.f + expf(-s));                 // silu
  float val = base * bf2f(xsrc[(size_t)g2[sub]*128 + c]);
  atomicAdd(&acc[(size_t)s2[sub]*128 + c], val);
}

// x = lrelu(x@Ws + (acc/max(deg,1))@Wn + b); xsum += x  (bf16, in place)
#define UPD_M 16
__global__ __launch_bounds__(256) void k_update(unsigned short* __restrict__ x,
    const float* __restrict__ accb, const float* __restrict__ deg,
    const float* __restrict__ Wss, const float* __restrict__ Wnn,
    const float* __restrict__ bias, unsigned short* __restrict__ xsum){
  __shared__ float xs[UPD_M][260];
  int tid = threadIdx.x, c = tid & 127, hh = tid >> 7;
  int nb = blockIdx.x * UPD_M;
  for (int m=0;m<UPD_M;m++){
    int n = nb + m;
    if (hh == 0) xs[m][c] = bf2f(x[(size_t)n*128 + c]);
    else         xs[m][128 + c] = accb[(size_t)n*128 + c] / fmaxf(deg[n], 1.f);
  }
  __syncthreads();
  int m0 = hh*8;
  float accv[8] = {0,0,0,0,0,0,0,0};
  for (int k=0;k<128;k+=4){
    float w0 = Wss[(k+0)*128+c], w1 = Wss[(k+1)*128+c],
          w2 = Wss[(k+2)*128+c], w3 = Wss[(k+3)*128+c];
    #pragma unroll
    for (int m=0;m<8;m++){
      const float4 xv = *(const float4*)&xs[m0+m][k];
      accv[m] += xv.x*w0 + xv.y*w1 + xv.z*w2 + xv.w*w3;
    }
  }
  for (int k=0;k<128;k+=4){
    float w0 = Wnn[(k+0)*128+c], w1 = Wnn[(k+1)*128+c],
          w2 = Wnn[(k+2)*128+c], w3 = Wnn[(k+3)*128+c];
    #pragma unroll
    for (int m=0;m<8;m++){
      const float4 xv = *(const float4*)&xs[m0+m][128+k];
      accv[m] += xv.x*w0 + xv.y*w1 + xv.z*w2 + xv.w*w3;
    }
  }
  float bc = bias[c];
  #pragma unroll
  for (int m=0;m<8;m++){
    int n = nb + m0 + m;
    float v = accv[m] + bc;
    v = (v > 0.f) ? v : 0.01f*v;
    size_t off = (size_t)n*128 + c;
    x[off] = f2bf(v);
    xsum[off] = f2bf(bf2f(xsum[off]) + v);
  }
}

// h = xsum @ W1part ([N,128]@[128,512]) -> bf16 rows (packed u32)
#define HP_M 16
__global__ __launch_bounds__(256) void k_hproj(const unsigned short* __restrict__ xsum,
    const float* __restrict__ W1p, unsigned* __restrict__ hout){
  __shared__ float xs[HP_M][132];
  int tid = threadIdx.x;
  int nb = blockIdx.x * HP_M;
  if (tid < 128){
    for (int m=0;m<HP_M;m++) xs[m][tid] = bf2f(xsum[(size_t)(nb+m)*128 + tid]);
  }
  __syncthreads();
  float a0[HP_M], a1[HP_M];
  #pragma unroll
  for (int m=0;m<HP_M;m++){ a0[m]=0.f; a1[m]=0.f; }
  int j2 = tid*2;
  for (int k=0;k<128;k+=4){
    float2 w0 = *(const float2*)&W1p[(k+0)*512 + j2];
    float2 w1 = *(const float2*)&W1p[(k+1)*512 + j2];
    float2 w2 = *(const float2*)&W1p[(k+2)*512 + j2];
    float2 w3 = *(const float2*)&W1p[(k+3)*512 + j2];
    #pragma unroll
    for (int m=0;m<HP_M;m++){
      const float4 xv = *(const float4*)&xs[m][k];
      a0[m] += xv.x*w0.x + xv.y*w1.x + xv.z*w2.x + xv.w*w3.x;
      a1[m] += xv.x*w0.y + xv.y*w1.y + xv.z*w2.y + xv.w*w3.y;
    }
  }
  #pragma unroll
  for (int m=0;m<HP_M;m++){
    unsigned pack = (unsigned)f2bf(a0[m]) | ((unsigned)f2bf(a1[m]) << 16);
    hout[(size_t)(nb+m)*256 + tid] = pack;
  }
}

// ---- MFMA readout: 32 sorted edges/block, 4 waves, 16x16x32 bf16 MFMA ----
// h = relu(hl[s]+hp[d]+d*v+b1) -> LDS bf16 [32][512]
// m = h@W2+b2 (MFMA, K=512); t = tanh(bf16(m)@Wm+bm) (MFMA, K=128)
// run-length flush of sum(t*m) / max(m) per batch (edges sorted by batch).
#define RO_ME 32
__global__ __launch_bounds__(256) void k_readout_mfma(
    const unsigned* __restrict__ hl, const unsigned* __restrict__ hp,
    const float* __restrict__ ea_s, const int* __restrict__ es_s,
    const int* __restrict__ ed_s, const int* __restrict__ eb_s,
    const float* __restrict__ vvec, const float* __restrict__ b1,
    const unsigned short* __restrict__ w2t, const float* __restrict__ b2,
    const unsigned short* __restrict__ wmt, const float* __restrict__ bm,
    float* __restrict__ outw, unsigned* __restrict__ mmax){
  __shared__ unsigned short hbuf[RO_ME][520];   // 520: row = 65x16B, 2-way-free banks
  __shared__ float ms[RO_ME][132];              // m fp32
  __shared__ unsigned short msb[RO_ME][136];    // m bf16 (GEMM2 A operand)
  __shared__ float wmp[RO_ME][132];             // t*m
  __shared__ int sidx[RO_ME], didx[RO_ME], bsh[RO_ME];
  __shared__ float dsts[RO_ME];

  int tid = threadIdx.x;
  int e0 = blockIdx.x * RO_ME;
  if (tid < RO_ME){
    int e = e0 + tid;
    sidx[tid] = es_s[e]; didx[tid] = ed_s[e];
    dsts[tid] = ea_s[e]; bsh[tid] = eb_s[e];
  }
  int j2 = tid*2;
  float2 vv = *(const float2*)&vvec[j2];
  float2 bv = *(const float2*)&b1[j2];
  __syncthreads();

  // stage h rows (bf16) into LDS
  for (int i=0;i<RO_ME;i++){
    unsigned ua = hl[(size_t)sidx[i]*256 + tid];
    unsigned ub = hp[(size_t)didx[i]*256 + tid];
    float dd = dsts[i];
    float hx = fmaxf(bflo(ua) + bflo(ub) + dd*vv.x + bv.x, 0.f);
    float hy = fmaxf(bfhi(ua) + bfhi(ub) + dd*vv.y + bv.y, 0.f);
    unsigned pack = (unsigned)f2bf(hx) | ((unsigned)f2bf(hy) << 16);
    *(unsigned*)&hbuf[i][j2] = pack;
  }
  __syncthreads();

  int wave = tid >> 6, lane = tid & 63;
  int quad = lane >> 4, l15 = lane & 15;
  int mt = wave & 1;              // M-tile: rows mt*16..+16
  int ns = (wave >> 1) * 64;      // N-strip: cols ns..ns+64

  // GEMM1: m[32,128] = h[32,512] @ W2 + b2
  float4v acc[4] = {{0,0,0,0},{0,0,0,0},{0,0,0,0},{0,0,0,0}};
  int arow = mt*16 + l15;
  for (int k0 = 0; k0 < 512; k0 += 32){
    short8 a = *(const short8*)&hbuf[arow][k0 + quad*8];
    #pragma unroll
    for (int nt=0;nt<4;nt++){
      short8 b = *(const short8*)&w2t[(size_t)(ns + nt*16 + l15)*512 + k0 + quad*8];
      acc[nt] = __builtin_amdgcn_mfma_f32_16x16x32_bf16(a, b, acc[nt], 0, 0, 0);
    }
  }
  #pragma unroll
  for (int nt=0;nt<4;nt++){
    int col = ns + nt*16 + l15;
    float b2c = b2[col];
    #pragma unroll
    for (int r=0;r<4;r++){
      int row = mt*16 + quad*4 + r;
      float mv = acc[nt][r] + b2c;
      ms[row][col] = mv;
      msb[row][col] = f2bf(mv);
    }
  }
  __syncthreads();

  // GEMM2: t = tanh(m@Wm + bm); wmp = t*m
  float4v acc2[4] = {{0,0,0,0},{0,0,0,0},{0,0,0,0},{0,0,0,0}};
  for (int k0 = 0; k0 < 128; k0 += 32){
    short8 a = *(const short8*)&msb[arow][k0 + quad*8];
    #pragma unroll
    for (int nt=0;nt<4;nt++){
      short8 b = *(const short8*)&wmt[(size_t)(ns + nt*16 + l15)*128 + k0 + quad*8];
      acc2[nt] = __builtin_amdgcn_mfma_f32_16x16x32_bf16(a, b, acc2[nt], 0, 0, 0);
    }
  }
  #pragma unroll
  for (int nt=0;nt<4;nt++){
    int col = ns + nt*16 + l15;
    float bmc = bm[col];
    #pragma unroll
    for (int r=0;r<4;r++){
      int row = mt*16 + quad*4 + r;
      float t = tanhf(acc2[nt][r] + bmc);
      wmp[row][col] = t * ms[row][col];
    }
  }
  __syncthreads();

  // run-length segment flush (edges sorted by batch; wave-uniform branches)
  int c = tid & 127, half = tid >> 7;
  int i0 = half*16;
  int curb = bsh[i0];
  float s = 0.f, mx = -3.402823466e38f;
  #pragma unroll
  for (int i=0;i<16;i++){
    int b = bsh[i0+i];
    float wv = wmp[i0+i][c];
    float mv = ms[i0+i][c];
    if (b != curb){
      atomicAdd(&outw[curb*256 + c], s);
      atomicMax(&mmax[curb*128 + c], encf(mx));
      curb = b; s = 0.f; mx = -3.402823466e38f;
    }
    s += wv; mx = fmaxf(mx, mv);
  }
  atomicAdd(&outw[curb*256 + c], s);
  atomicMax(&mmax[curb*128 + c], encf(mx));
}

__global__ __launch_bounds__(256) void k_final(const unsigned* __restrict__ mmax,
    float* __restrict__ out){
  int gid = blockIdx.x*256 + threadIdx.x;   // 32768 = 256*128
  unsigned enc = mmax[gid];
  float v;
  if (enc == 0u) v = 0.f;
  else if (enc & 0x80000000u) v = __uint_as_float(enc & 0x7FFFFFFFu);
  else v = __uint_as_float(~enc);
  int g = gid >> 7, cc = gid & 127;
  out[g*256 + 128 + cc] = v;
}

extern "C" void kernel_launch(void* const* d_in, const int* in_sizes, int n_in,
                              void* d_out, int out_size, void* d_ws, size_t ws_size,
                              hipStream_t stream) {
  const float* x_l    = (const float*)d_in[0];
  const float* x_p    = (const float*)d_in[1];
  const float* ea     = (const float*)d_in[2];
  const int*   esrc   = (const int*)d_in[3];
  const int*   edst   = (const int*)d_in[4];
  const int*   lbatch = (const int*)d_in[5];
  const float* W_node = (const float*)d_in[6];
  const float* W_el   = (const float*)d_in[7];
  const float* Wb     = (const float*)d_in[8];
  const float* bb     = (const float*)d_in[9];
  const float* Wn     = (const float*)d_in[10];
  const float* Ws     = (const float*)d_in[11];
  const float* bconv  = (const float*)d_in[12];
  const float* W1     = (const float*)d_in[13];
  const float* b1     = (const float*)d_in[14];
  const float* W2     = (const float*)d_in[15];
  const float* b2     = (const float*)d_in[16];
  const float* Wm     = (const float*)d_in[17];
  const float* bm     = (const float*)d_in[18];

  // ---- workspace layout (decimal offsets), peak 265,165,888 B = 252.9 MiB ----
  // Phase A (conv loop):              Phase B (readout), time-aliased:
  //   [0       ..  12.8e6) xl bf16      [0      ..  51.2e6) h_l bf16
  //   [12.8e6  ..  51.2e6) xp bf16      [51.2e6 .. 204.8e6) h_p bf16
  //   [51.2e6  ..  76.8e6) acc_l f32
  //   [76.8e6  .. 153.6e6) acc_p f32
  // persistent: xl_s/xp_s [204.8e6..256.0e6), deg [256.0e6..256.8e6),
  //   vvec [256.8e6..+2048), mmax [256,802,048..+131072)
  // sorted edges + bf16 weights: [257.0e6 .. 265,165,888)
  char* w = (char*)d_ws;
  unsigned short* xl   = (unsigned short*)(w + 0);
  unsigned short* xp   = (unsigned short*)(w + 12800000);
  float*    acc_l = (float*)(w + 51200000);
  float*    acc_p = (float*)(w + 76800000);
  unsigned* h_l   = (unsigned*)(w + 0);
  unsigned* h_p   = (unsigned*)(w + 51200000);
  unsigned short* xl_s = (unsigned short*)(w + 204800000);
  unsigned short* xp_s = (unsigned short*)(w + 217600000);
  float*    deg_l = (float*)(w + 256000000);
  float*    deg_p = (float*)(w + 256200000);
  float*    vvec  = (float*)(w + 256800000);
  unsigned* mmax  = (unsigned*)(w + 256802048);
  int*      es_s  = (int*)(w + 257000000);
  int*      ed_s  = (int*)(w + 259000000);
  int*      eb_s  = (int*)(w + 261000000);
  float*    ea_s  = (float*)(w + 263000000);
  unsigned short* w2t = (unsigned short*)(w + 265000000);
  unsigned short* wmt = (unsigned short*)(w + 265131072);
  unsigned* hist   = (unsigned*)(w + 265163840);
  unsigned* cursor = (unsigned*)(w + 265164864);

  float* out = (float*)d_out;

  k_zero<<<1024, 256, 0, stream>>>((unsigned*)(w + 204800000), 51200000/4); // xl_s+xp_s
  k_zero<<<256, 256, 0, stream>>>((unsigned*)(w + 256000000), 800000/4);    // deg
  k_zero<<<128, 256, 0, stream>>>(mmax, 131072/4);
  k_zero<<<256, 256, 0, stream>>>((unsigned*)d_out, 262144/4);
  k_zero<<<2, 256, 0, stream>>>(hist, 2048/4);                              // hist+cursor

  k_embed<<<25000, 256, 0, stream>>>(x_l, W_node, xl);
  k_embed<<<75000, 256, 0, stream>>>(x_p, W_node, xp);
  k_deg<<<(En+255)/256, 256, 0, stream>>>(esrc, edst, deg_l, deg_p);
  k_vvec<<<2, 256, 0, stream>>>(W_el, W1, vvec);
  k_w2t<<<256, 256, 0, stream>>>(W2, w2t);
  k_wmt<<<64, 256, 0, stream>>>(Wm, wmt);

  k_hist<<<(En+255)/256, 256, 0, stream>>>(esrc, lbatch, hist);
  k_scan<<<1, 256, 0, stream>>>(hist, cursor);
  k_sortscatter<<<(En+255)/256, 256, 0, stream>>>(esrc, edst, ea, lbatch, cursor,
                                                  es_s, ed_s, ea_s, eb_s);

  for (int l = 0; l < 3; ++l){
    int ilp = 2*l, ipl = 2*l + 1;
    k_zero<<<2048, 256, 0, stream>>>((unsigned*)(w + 51200000), 102400000/4); // acc_l+acc_p
    k_scatter<<<En/2, 256, 0, stream>>>(ea, esrc, edst, xl, acc_p,
                                        Wb + ilp*1024, bb + ilp*128);
    k_scatter<<<En/2, 256, 0, stream>>>(ea, edst, esrc, xp, acc_l,
                                        Wb + ipl*1024, bb + ipl*128);
    k_update<<<NPn/UPD_M, 256, 0, stream>>>(xp, acc_p, deg_p,
        Ws + ilp*16384, Wn + ilp*16384, bconv + ilp*128, xp_s);
    k_update<<<NLn/UPD_M, 256, 0, stream>>>(xl, acc_l, deg_l,
        Ws + ipl*16384, Wn + ipl*16384, bconv + ipl*128, xl_s);
  }

  k_hproj<<<NLn/HP_M, 256, 0, stream>>>(xl_s, W1, h_l);            // W1 rows 0..127
  k_hproj<<<NPn/HP_M, 256, 0, stream>>>(xp_s, W1 + 128*512, h_p);  // W1 rows 128..255

  k_readout_mfma<<<En/RO_ME, 256, 0, stream>>>(h_l, h_p, ea_s, es_s, ed_s, eb_s,
                                               vvec, b1, w2t, b2, wmt, bm, out, mmax);
  k_final<<<128, 256, 0, stream>>>(mmax, out);
}

// Round 4
// 2869.078 us; speedup vs baseline: 1.8741x; 1.5171x over previous
//
#include <hip/hip_runtime.h>
#include <hip/hip_bf16.h>

// HeteroNet on MI355X — round 4: CSR-based atomic-free convs w/ MFMA updates,
// MFMA hproj, readout LDS-union (occupancy 2->3 blocks/CU).
// R3 profile: readout 704us latency-bound (MfmaUtil 4.6, VALU 18.6, occ 23%);
// ~3.6ms in scatter(atomics)/update(fp32 VALU)/hproj(fp32 VALU).

#define NLn 50000
#define NPn 150000
#define En  500000

typedef __attribute__((ext_vector_type(8))) short short8;
typedef __attribute__((ext_vector_type(4))) float float4v;

__device__ __forceinline__ float bf2f(unsigned short u){ return __uint_as_float(((unsigned)u) << 16); }
__device__ __forceinline__ float bflo(unsigned u){ return __uint_as_float(u << 16); }
__device__ __forceinline__ float bfhi(unsigned u){ return __uint_as_float(u & 0xffff0000u); }
__device__ __forceinline__ unsigned short f2bf(float f){
  __hip_bfloat16 h = __float2bfloat16(f);
  return *reinterpret_cast<unsigned short*>(&h);
}
// order-preserving float->uint; enc(v)>0 for all finite v, so 0 == "empty segment"
__device__ __forceinline__ unsigned encf(float f){
  unsigned u = __float_as_uint(f);
  return (u & 0x80000000u) ? ~u : (u | 0x80000000u);
}

__global__ __launch_bounds__(256) void k_zero(unsigned* __restrict__ p, long n){
  long i = (long)blockIdx.x*256 + threadIdx.x;
  long stride = (long)gridDim.x*256;
  for (; i < n; i += stride) p[i] = 0u;
}

// out[n,c] = sum_k X[n,k]*W[k,c]  ([N,44]@[44,128]) -> bf16
__global__ __launch_bounds__(256) void k_embed(const float* __restrict__ X,
    const float* __restrict__ Wn, unsigned short* __restrict__ out){
  int gid = blockIdx.x*256 + threadIdx.x;
  int n = gid >> 7, c = gid & 127;
  const float* xr = X + (size_t)n*44;
  float acc = 0.f;
  #pragma unroll
  for (int k=0;k<44;k++) acc += xr[k]*Wn[k*128+c];
  out[(size_t)n*128 + c] = f2bf(acc);
}

// v[j] = sum_r W_el[r] * W1[(256+r)*512 + j]
__global__ void k_vvec(const float* __restrict__ Wel, const float* __restrict__ W1,
                       float* __restrict__ v){
  int j = blockIdx.x*256 + threadIdx.x;
  if (j >= 512) return;
  float s = 0.f;
  #pragma unroll
  for (int r=0;r<8;r++) s += Wel[r]*W1[(256+r)*512 + j];
  v[j] = s;
}

// w2t[n][k] = bf16(W2[k][n])   (512x128 -> 128x512)
__global__ __launch_bounds__(256) void k_w2t(const float* __restrict__ W2,
    unsigned short* __restrict__ w2t){
  int gid = blockIdx.x*256 + threadIdx.x;   // 65536
  int n = gid >> 9, k = gid & 511;
  w2t[n*512 + k] = f2bf(W2[k*128 + n]);
}
// wmt[n][k] = bf16(Wm[k][n])   (128x128)
__global__ __launch_bounds__(256) void k_wmt(const float* __restrict__ Wm,
    unsigned short* __restrict__ wmt){
  int gid = blockIdx.x*256 + threadIdx.x;   // 16384
  int n = gid >> 7, k = gid & 127;
  wmt[n*128 + k] = f2bf(Wm[k*128 + n]);
}
// wcat[i][n][k] = bf16( k<128 ? Ws[i][k][n] : Wn[i][k-128][n] )   (6x128x256)
__global__ __launch_bounds__(256) void k_wcat(const float* __restrict__ Ws,
    const float* __restrict__ Wn, unsigned short* __restrict__ wcat){
  int gid = blockIdx.x*256 + threadIdx.x;   // 196608
  int i = gid >> 15, rem = gid & 32767;
  int n = rem >> 8, k = rem & 255;
  float v = (k < 128) ? Ws[i*16384 + k*128 + n] : Wn[i*16384 + (k-128)*128 + n];
  wcat[gid] = f2bf(v);
}
// w1t[part][n][k] = bf16(W1[part*128+k][n])  part 0: ligand rows, 1: protein rows
__global__ __launch_bounds__(256) void k_w1t(const float* __restrict__ W1,
    unsigned short* __restrict__ w1t){
  int gid = blockIdx.x*256 + threadIdx.x;   // 131072 = 2*512*128
  int part = gid >> 16, rem = gid & 65535;
  int n = rem >> 7, k = rem & 127;
  w1t[gid] = f2bf(W1[(part*128 + k)*512 + n]);
}

// ---- CSR construction ----
__global__ __launch_bounds__(256) void k_count(const int* __restrict__ esrc,
    const int* __restrict__ edst, unsigned* __restrict__ cntL, unsigned* __restrict__ cntP){
  int e = blockIdx.x*256 + threadIdx.x;
  if (e >= En) return;
  atomicAdd(&cntL[esrc[e]], 1u);
  atomicAdd(&cntP[edst[e]], 1u);
}
// per-1024-chunk local exclusive scan; chunk totals to bsum
__global__ __launch_bounds__(256) void k_chunkscan(const unsigned* __restrict__ cnt,
    unsigned* __restrict__ rowptr, unsigned* __restrict__ bsum, int n){
  __shared__ unsigned ts[256];
  int tid = threadIdx.x;
  int base = blockIdx.x*1024 + tid*4;
  unsigned v[4], run = 0;
  #pragma unroll
  for (int j=0;j<4;j++){ v[j] = run; run += (base+j < n) ? cnt[base+j] : 0u; }
  ts[tid] = run; __syncthreads();
  for (int off=1; off<256; off<<=1){
    unsigned t = (tid>=off) ? ts[tid-off] : 0u; __syncthreads();
    ts[tid] += t; __syncthreads();
  }
  unsigned excl = ts[tid] - run;
  #pragma unroll
  for (int j=0;j<4;j++) if (base+j < n) rowptr[base+j] = excl + v[j];
  if (tid == 255) bsum[blockIdx.x] = ts[255];
}
// single block: exclusive scan over <=256 chunk totals (in place)
__global__ void k_scanb(unsigned* __restrict__ bsum, int nc){
  __shared__ unsigned ts[256];
  int tid = threadIdx.x;
  unsigned x = (tid < nc) ? bsum[tid] : 0u;
  ts[tid] = x; __syncthreads();
  for (int off=1; off<256; off<<=1){
    unsigned t = (tid>=off) ? ts[tid-off] : 0u; __syncthreads();
    ts[tid] += t; __syncthreads();
  }
  if (tid < nc) bsum[tid] = ts[tid] - x;
}
__global__ __launch_bounds__(256) void k_addoff(unsigned* __restrict__ rowptr,
    unsigned* __restrict__ cursor, const unsigned* __restrict__ bsum, int n){
  int i = blockIdx.x*256 + threadIdx.x;
  if (i < n){
    unsigned r = rowptr[i] + bsum[i>>10];
    rowptr[i] = r; cursor[i] = r;
  }
  if (i == 0) rowptr[n] = En;
}
// place edges into both CSR orders; precompute rbf (bf16 x8, packed uint4)
__global__ __launch_bounds__(256) void k_place(const int* __restrict__ esrc,
    const int* __restrict__ edst, const float* __restrict__ ea,
    const int* __restrict__ lbatch, unsigned* __restrict__ curL,
    unsigned* __restrict__ curP, uint4* __restrict__ edgeL,
    uint4* __restrict__ rbfL, int* __restrict__ srcP, uint4* __restrict__ rbfP){
  int e = blockIdx.x*256 + threadIdx.x;
  if (e >= En) return;
  int s = esrc[e], d = edst[e];
  float dd = ea[e];
  unsigned short r[8];
  #pragma unroll
  for (int j=0;j<8;j++){
    float a = (dd - 0.7142857143f*(float)j) * 1.6f;   // mu=linspace(0,5,8), sigma=5/8
    r[j] = f2bf(__expf(-a*a));
  }
  uint4 rp;
  rp.x = (unsigned)r[0] | ((unsigned)r[1]<<16);
  rp.y = (unsigned)r[2] | ((unsigned)r[3]<<16);
  rp.z = (unsigned)r[4] | ((unsigned)r[5]<<16);
  rp.w = (unsigned)r[6] | ((unsigned)r[7]<<16);
  unsigned pl = atomicAdd(&curL[s], 1u);
  uint4 er; er.x = (unsigned)s; er.y = (unsigned)d;
  er.z = __float_as_uint(dd); er.w = (unsigned)lbatch[s];
  edgeL[pl] = er; rbfL[pl] = rp;
  unsigned pp = atomicAdd(&curP[d], 1u);
  srcP[pp] = s; rbfP[pp] = rp;
}

// ---- fused conv: CSR aggregate + MFMA update, 32 dst nodes per block ----
// agg[n] = (1/max(deg,1)) * sum_e silu(rbf_e@Wb+bb) * x_src[e]
// out = lrelu([x_dst|agg] @ wcat + bias); xout = out; xsum += out
__global__ __launch_bounds__(256) void k_conv(
    const unsigned short* __restrict__ xdst_in, const unsigned short* __restrict__ xsrc_in,
    const unsigned* __restrict__ rowptr, const int* __restrict__ eidx, int estride,
    const uint4* __restrict__ rbfpk,
    const float* __restrict__ Wb_i, const float* __restrict__ bb_i,
    const unsigned short* __restrict__ wcat, const float* __restrict__ bias,
    unsigned short* __restrict__ xout, unsigned short* __restrict__ xsum, int ndst){
  __shared__ unsigned short ab[32][264];   // [m][k]: k<128 x_dst, k>=128 agg (bf16)
  __shared__ float ob[32][132];
  int tid = threadIdx.x, c = tid & 127, hh = tid >> 7;
  int n0 = blockIdx.x*32;
  float wb[8];
  #pragma unroll
  for (int j=0;j<8;j++) wb[j] = Wb_i[j*128 + c];
  float bbc = bb_i[c];
  for (int m = hh*16; m < hh*16+16; m++){
    int n = n0 + m;
    float a = 0.f;
    if (n < ndst){
      ab[m][c] = xdst_in[(size_t)n*128 + c];
      unsigned r0 = rowptr[n], r1 = rowptr[n+1];
      for (unsigned p = r0; p < r1; p++){
        uint4 rp = rbfpk[p];                       // wave-uniform 16B
        int sn = eidx[(size_t)p*estride];
        const unsigned short* rs = (const unsigned short*)&rp;
        float s = bbc;
        #pragma unroll
        for (int j=0;j<8;j++) s += bf2f(rs[j])*wb[j];
        float base = s / (1.f + __expf(-s));       // silu
        a += base * bf2f(xsrc_in[(size_t)sn*128 + c]);
      }
      int dg = (int)(r1 - r0);
      a *= 1.f / (float)(dg > 1 ? dg : 1);
    } else {
      ab[m][c] = 0;
    }
    ab[m][128 + c] = f2bf(a);
  }
  __syncthreads();
  int wave = tid >> 6, lane = tid & 63, quad = lane >> 4, l15 = lane & 15;
  int mt = wave & 1, nh = wave >> 1;
  int arow = mt*16 + l15;
  float4v acc[4] = {{0,0,0,0},{0,0,0,0},{0,0,0,0},{0,0,0,0}};
  for (int k0 = 0; k0 < 256; k0 += 32){
    short8 A = *(const short8*)&ab[arow][k0 + quad*8];
    #pragma unroll
    for (int nt=0;nt<4;nt++){
      short8 B = *(const short8*)&wcat[(size_t)(nh*64 + nt*16 + l15)*256 + k0 + quad*8];
      acc[nt] = __builtin_amdgcn_mfma_f32_16x16x32_bf16(A, B, acc[nt], 0, 0, 0);
    }
  }
  #pragma unroll
  for (int nt=0;nt<4;nt++){
    int col = nh*64 + nt*16 + l15;
    float bc = bias[col];
    #pragma unroll
    for (int r=0;r<4;r++){
      int row = mt*16 + quad*4 + r;
      float v = acc[nt][r] + bc;
      ob[row][col] = (v > 0.f) ? v : 0.01f*v;      // leaky_relu
    }
  }
  __syncthreads();
  for (int m = hh*16; m < hh*16+16; m++){
    int n = n0 + m;
    if (n < ndst){
      float v = ob[m][c];
      size_t off = (size_t)n*128 + c;
      xout[off] = f2bf(v);
      xsum[off] = f2bf(bf2f(xsum[off]) + v);
    }
  }
}

// ---- MFMA hproj: h[n][512] = xsum[n][128] @ w1t^T, 32 nodes/block ----
__global__ __launch_bounds__(256) void k_hproj_mfma(
    const unsigned short* __restrict__ xs, const unsigned short* __restrict__ w1t,
    unsigned* __restrict__ hout, int nn){
  __shared__ unsigned short hb[32][528];
  int tid = threadIdx.x;
  int wave = tid >> 6, lane = tid & 63, quad = lane >> 4, l15 = lane & 15;
  int mt = wave & 1, nh = wave >> 1;
  int n0 = blockIdx.x*32;
  int an = n0 + mt*16 + l15; if (an >= nn) an = nn - 1;
  const unsigned short* aptr = xs + (size_t)an*128;
  float4v acc[16];
  #pragma unroll
  for (int i=0;i<16;i++) acc[i] = (float4v){0,0,0,0};
  for (int k0 = 0; k0 < 128; k0 += 32){
    short8 A = *(const short8*)&aptr[k0 + quad*8];
    #pragma unroll
    for (int nt=0;nt<16;nt++){
      short8 B = *(const short8*)&w1t[(size_t)(nh*256 + nt*16 + l15)*128 + k0 + quad*8];
      acc[nt] = __builtin_amdgcn_mfma_f32_16x16x32_bf16(A, B, acc[nt], 0, 0, 0);
    }
  }
  #pragma unroll
  for (int nt=0;nt<16;nt++){
    int col = nh*256 + nt*16 + l15;
    #pragma unroll
    for (int r=0;r<4;r++) hb[mt*16 + quad*4 + r][col] = f2bf(acc[nt][r]);
  }
  __syncthreads();
  for (int m=0;m<32;m++){
    int n = n0 + m;
    if (n < nn){
      unsigned pack = (unsigned)hb[m][2*tid] | ((unsigned)hb[m][2*tid+1] << 16);
      hout[(size_t)n*256 + tid] = pack;
    }
  }
}

// ---- MFMA readout: 32 esrc-sorted edges/block; union LDS (43KB -> 3 blk/CU) ----
#define RO_ME 32
__global__ __launch_bounds__(256) void k_readout_mfma(
    const unsigned* __restrict__ hl, const unsigned* __restrict__ hp,
    const uint4* __restrict__ edgeL,
    const float* __restrict__ vvec, const float* __restrict__ b1,
    const unsigned short* __restrict__ w2t, const float* __restrict__ b2,
    const unsigned short* __restrict__ wmt, const float* __restrict__ bm,
    float* __restrict__ outw, unsigned* __restrict__ mmax){
  __shared__ __align__(16) char smem[42496];
  unsigned short (*hbuf)[520] = (unsigned short(*)[520])smem;        // dead after GEMM1
  float (*ms)[132]            = (float(*)[132])smem;                 // aliases hbuf
  unsigned short (*msb)[136]  = (unsigned short(*)[136])(smem + 16896);
  float (*wmp)[132]           = (float(*)[132])(smem + 25600);
  __shared__ int sidx[RO_ME], didx[RO_ME], bsh[RO_ME];
  __shared__ float dsts[RO_ME];

  int tid = threadIdx.x;
  int e0 = blockIdx.x * RO_ME;
  if (tid < RO_ME){
    uint4 er = edgeL[e0 + tid];
    sidx[tid] = (int)er.x; didx[tid] = (int)er.y;
    dsts[tid] = __uint_as_float(er.z); bsh[tid] = (int)er.w;
  }
  int j2 = tid*2;
  float2 vv = *(const float2*)&vvec[j2];
  float2 bv = *(const float2*)&b1[j2];
  __syncthreads();

  for (int i=0;i<RO_ME;i++){
    unsigned ua = hl[(size_t)sidx[i]*256 + tid];
    unsigned ub = hp[(size_t)didx[i]*256 + tid];
    float dd = dsts[i];
    float hx = fmaxf(bflo(ua) + bflo(ub) + dd*vv.x + bv.x, 0.f);
    float hy = fmaxf(bfhi(ua) + bfhi(ub) + dd*vv.y + bv.y, 0.f);
    *(unsigned*)&hbuf[i][j2] = (unsigned)f2bf(hx) | ((unsigned)f2bf(hy) << 16);
  }
  __syncthreads();

  int wave = tid >> 6, lane = tid & 63, quad = lane >> 4, l15 = lane & 15;
  int mt = wave & 1, ns = (wave >> 1) * 64;
  int arow = mt*16 + l15;

  // GEMM1: m[32,128] = h[32,512] @ W2 + b2
  float4v acc[4] = {{0,0,0,0},{0,0,0,0},{0,0,0,0},{0,0,0,0}};
  for (int k0 = 0; k0 < 512; k0 += 32){
    short8 a = *(const short8*)&hbuf[arow][k0 + quad*8];
    #pragma unroll
    for (int nt=0;nt<4;nt++){
      short8 b = *(const short8*)&w2t[(size_t)(ns + nt*16 + l15)*512 + k0 + quad*8];
      acc[nt] = __builtin_amdgcn_mfma_f32_16x16x32_bf16(a, b, acc[nt], 0, 0, 0);
    }
  }
  __syncthreads();   // all waves done reading hbuf before ms/msb overwrite it
  #pragma unroll
  for (int nt=0;nt<4;nt++){
    int col = ns + nt*16 + l15;
    float b2c = b2[col];
    #pragma unroll
    for (int r=0;r<4;r++){
      int row = mt*16 + quad*4 + r;
      float mv = acc[nt][r] + b2c;
      ms[row][col] = mv;
      msb[row][col] = f2bf(mv);
    }
  }
  __syncthreads();

  // GEMM2: t = tanh(m@Wm + bm); wmp = t*m
  float4v acc2[4] = {{0,0,0,0},{0,0,0,0},{0,0,0,0},{0,0,0,0}};
  for (int k0 = 0; k0 < 128; k0 += 32){
    short8 a = *(const short8*)&msb[arow][k0 + quad*8];
    #pragma unroll
    for (int nt=0;nt<4;nt++){
      short8 b = *(const short8*)&wmt[(size_t)(ns + nt*16 + l15)*128 + k0 + quad*8];
      acc2[nt] = __builtin_amdgcn_mfma_f32_16x16x32_bf16(a, b, acc2[nt], 0, 0, 0);
    }
  }
  #pragma unroll
  for (int nt=0;nt<4;nt++){
    int col = ns + nt*16 + l15;
    float bmc = bm[col];
    #pragma unroll
    for (int r=0;r<4;r++){
      int row = mt*16 + quad*4 + r;
      float t = tanhf(acc2[nt][r] + bmc);
      wmp[row][col] = t * ms[row][col];
    }
  }
  __syncthreads();

  // run-length segment flush (edges sorted by batch)
  int c = tid & 127, half = tid >> 7;
  int i0 = half*16;
  int curb = bsh[i0];
  float s = 0.f, mx = -3.402823466e38f;
  #pragma unroll
  for (int i=0;i<16;i++){
    int b = bsh[i0+i];
    float wv = wmp[i0+i][c];
    float mv = ms[i0+i][c];
    if (b != curb){
      atomicAdd(&outw[curb*256 + c], s);
      atomicMax(&mmax[curb*128 + c], encf(mx));
      curb = b; s = 0.f; mx = -3.402823466e38f;
    }
    s += wv; mx = fmaxf(mx, mv);
  }
  atomicAdd(&outw[curb*256 + c], s);
  atomicMax(&mmax[curb*128 + c], encf(mx));
}

__global__ __launch_bounds__(256) void k_final(const unsigned* __restrict__ mmax,
    float* __restrict__ out){
  int gid = blockIdx.x*256 + threadIdx.x;   // 32768 = 256*128
  unsigned enc = mmax[gid];
  float v;
  if (enc == 0u) v = 0.f;
  else if (enc & 0x80000000u) v = __uint_as_float(enc & 0x7FFFFFFFu);
  else v = __uint_as_float(~enc);
  int g = gid >> 7, cc = gid & 127;
  out[g*256 + 128 + cc] = v;
}

extern "C" void kernel_launch(void* const* d_in, const int* in_sizes, int n_in,
                              void* d_out, int out_size, void* d_ws, size_t ws_size,
                              hipStream_t stream) {
  const float* x_l    = (const float*)d_in[0];
  const float* x_p    = (const float*)d_in[1];
  const float* ea     = (const float*)d_in[2];
  const int*   esrc   = (const int*)d_in[3];
  const int*   edst   = (const int*)d_in[4];
  const int*   lbatch = (const int*)d_in[5];
  const float* W_node = (const float*)d_in[6];
  const float* W_el   = (const float*)d_in[7];
  const float* Wb     = (const float*)d_in[8];
  const float* bb     = (const float*)d_in[9];
  const float* Wn     = (const float*)d_in[10];
  const float* Ws     = (const float*)d_in[11];
  const float* bconv  = (const float*)d_in[12];
  const float* W1     = (const float*)d_in[13];
  const float* b1     = (const float*)d_in[14];
  const float* W2     = (const float*)d_in[15];
  const float* b2     = (const float*)d_in[16];
  const float* Wm     = (const float*)d_in[17];
  const float* bm     = (const float*)d_in[18];

  // ---- workspace layout (decimal offsets), peak 267,354,496 B < 256 MiB ----
  // Region A [0,204.8e6): conv phase: xl0/xl1/xp0/xp1 + srcP/rbfP/rbfL (conv-only)
  //                       readout phase (after convs): h_l [0,51.2e6), h_p [51.2,204.8)e6
  char* w = (char*)d_ws;
  unsigned short* xl0 = (unsigned short*)(w + 0);
  unsigned short* xl1 = (unsigned short*)(w + 12800000);
  unsigned short* xp0 = (unsigned short*)(w + 25600000);
  unsigned short* xp1 = (unsigned short*)(w + 64000000);
  int*      srcP  = (int*)(w + 102400000);
  uint4*    rbfP  = (uint4*)(w + 104400000);
  uint4*    rbfL  = (uint4*)(w + 112400000);
  unsigned* h_l   = (unsigned*)(w + 0);
  unsigned* h_p   = (unsigned*)(w + 51200000);
  unsigned short* xl_s = (unsigned short*)(w + 204800000);
  unsigned short* xp_s = (unsigned short*)(w + 217600000);
  unsigned short* wcat = (unsigned short*)(w + 256000000);
  unsigned short* w1t  = (unsigned short*)(w + 256393216);  // part l at +0, part p at +65536 shorts
  unsigned short* w2t  = (unsigned short*)(w + 256655360);
  unsigned short* wmt  = (unsigned short*)(w + 256786432);
  float*    vvec  = (float*)(w + 256819200);
  unsigned* mmax  = (unsigned*)(w + 256821248);
  unsigned* bsumL = (unsigned*)(w + 256952320);
  unsigned* bsumP = (unsigned*)(w + 256953344);
  unsigned* rowptrL = (unsigned*)(w + 256954368);
  unsigned* cursorL = (unsigned*)(w + 257154432);
  unsigned* rowptrP = (unsigned*)(w + 257354432);
  unsigned* cursorP = (unsigned*)(w + 257954496);
  unsigned* cntL    = (unsigned*)(w + 258554496);
  unsigned* cntP    = (unsigned*)(w + 258754496);
  uint4*    edgeL   = (uint4*)(w + 259354496);   // {src, dst, bits(d), batch} per edge

  float* out = (float*)d_out;

  k_zero<<<1024, 256, 0, stream>>>((unsigned*)(w + 204800000), 51200000/4);  // xl_s+xp_s
  k_zero<<<196, 256, 0, stream>>>((unsigned*)(w + 258554496), 800000/4);     // cntL+cntP
  k_zero<<<128, 256, 0, stream>>>(mmax, 131072/4);
  k_zero<<<256, 256, 0, stream>>>((unsigned*)d_out, 262144/4);

  k_embed<<<25000, 256, 0, stream>>>(x_l, W_node, xl0);
  k_embed<<<75000, 256, 0, stream>>>(x_p, W_node, xp0);
  k_vvec<<<2, 256, 0, stream>>>(W_el, W1, vvec);
  k_w2t<<<256, 256, 0, stream>>>(W2, w2t);
  k_wmt<<<64, 256, 0, stream>>>(Wm, wmt);
  k_wcat<<<768, 256, 0, stream>>>(Ws, Wn, wcat);
  k_w1t<<<512, 256, 0, stream>>>(W1, w1t);

  k_count<<<1954, 256, 0, stream>>>(esrc, edst, cntL, cntP);
  k_chunkscan<<<49, 256, 0, stream>>>(cntL, rowptrL, bsumL, NLn);
  k_chunkscan<<<147, 256, 0, stream>>>(cntP, rowptrP, bsumP, NPn);
  k_scanb<<<1, 256, 0, stream>>>(bsumL, 49);
  k_scanb<<<1, 256, 0, stream>>>(bsumP, 147);
  k_addoff<<<196, 256, 0, stream>>>(rowptrL, cursorL, bsumL, NLn);
  k_addoff<<<586, 256, 0, stream>>>(rowptrP, cursorP, bsumP, NPn);
  k_place<<<1954, 256, 0, stream>>>(esrc, edst, ea, lbatch, cursorL, cursorP,
                                    edgeL, rbfL, srcP, rbfP);

  unsigned short *xlc = xl0, *xln = xl1, *xpc = xp0, *xpn = xp1;
  for (int l = 0; l < 3; ++l){
    int ilp = 2*l, ipl = 2*l + 1;
    // protein update: dst=protein (CSR-P), gather ligand x
    k_conv<<<4688, 256, 0, stream>>>(xpc, xlc, rowptrP, srcP, 1, rbfP,
        Wb + ilp*1024, bb + ilp*128, wcat + ilp*32768, bconv + ilp*128,
        xpn, xp_s, NPn);
    // ligand update: dst=ligand (CSR-L), gather protein x (edgeL.y, stride 4)
    k_conv<<<1563, 256, 0, stream>>>(xlc, xpc, rowptrL, (const int*)edgeL + 1, 4, rbfL,
        Wb + ipl*1024, bb + ipl*128, wcat + ipl*32768, bconv + ipl*128,
        xln, xl_s, NLn);
    unsigned short* t;
    t = xlc; xlc = xln; xln = t;
    t = xpc; xpc = xpn; xpn = t;
  }

  k_hproj_mfma<<<1563, 256, 0, stream>>>(xl_s, w1t, h_l, NLn);
  k_hproj_mfma<<<4688, 256, 0, stream>>>(xp_s, w1t + 65536, h_p, NPn);

  k_readout_mfma<<<En/RO_ME, 256, 0, stream>>>(h_l, h_p, edgeL,
      vvec, b1, w2t, b2, wmt, bm, out, mmax);
  k_final<<<128, 256, 0, stream>>>(mmax, out);
}